// Round 10
// baseline (454.150 us; speedup 1.0000x reference)
//
#include <hip/hip_runtime.h>
#include <hip/hip_bf16.h>

typedef __hip_bfloat16 bf16;
typedef _Float16 f16;
typedef __attribute__((ext_vector_type(8))) short short8;
typedef __attribute__((ext_vector_type(4))) float f32x4;
typedef __attribute__((ext_vector_type(8))) _Float16 f16x8;
typedef __attribute__((ext_vector_type(4))) _Float16 f16x4;

#define Q_LEN 1024
#define B_SZ 4
#define DM 1024
#define H_CNT 16
#define HD 64
#define MEM_LEN 512
#define KLEN 1536
#define MLP 4096

__device__ __forceinline__ void store_c(float* p, float v) { *p = v; }
__device__ __forceinline__ void store_c(bf16* p, float v) { *p = __float2bfloat16(v); }
__device__ __forceinline__ void store_c(f16* p, float v) { *p = (f16)v; }

__device__ __forceinline__ float b2f(short s) {
  union { unsigned u; float f; } x;
  x.u = ((unsigned)(unsigned short)s) << 16;
  return x.f;
}
__device__ __forceinline__ short f2b(float f) {
  union { float f; unsigned u; } x;
  x.f = f;
  unsigned r = x.u + 0x7fff + ((x.u >> 16) & 1);  // RNE; inputs finite
  return (short)(r >> 16);
}

// async global->LDS, 16B per lane; LDS dest = wave-uniform base + lane*16
__device__ __forceinline__ void gload16(const void* g, void* l) {
  __builtin_amdgcn_global_load_lds(
      (__attribute__((address_space(1))) unsigned int*)(g),
      (__attribute__((address_space(3))) unsigned int*)(l), 16, 0, 0);
}

// ------- merged fp32 -> fp16 convert: 3 segments in one launch -------
__global__ __launch_bounds__(256) void convh3_kernel(
    const float* __restrict__ X0, const float* __restrict__ X1,
    const float* __restrict__ X2, f16* __restrict__ Y0,
    f16* __restrict__ Y1, f16* __restrict__ Y2) {
  const int blk = blockIdx.x, tid = threadIdx.x;
  const float* X;
  f16* Y;
  int i;
  if (blk < 2048) { X = X0; Y = Y0; i = blk * 256 + tid; }
  else if (blk < 6144) { X = X1; Y = Y1; i = (blk - 2048) * 256 + tid; }
  else { X = X2; Y = Y2; i = (blk - 6144) * 256 + tid; }
  f32x4 v = *(const f32x4*)&X[(size_t)i * 4];
  f16x4 h;
#pragma unroll
  for (int j = 0; j < 4; ++j) h[j] = (f16)v[j];
  *(f16x4*)&Y[(size_t)i * 4] = h;
}

// ------- merged fp32 [K][N] -> fp16 [N][K] transpose: 3 descriptors -------
__global__ __launch_bounds__(256) void convTm_kernel(
    const float* W0, f16* T0, int K0, int N0, int nx0,
    int s1, const float* W1p, f16* T1, int K1, int N1, int nx1,
    int s2, const float* W2p, f16* T2, int K2, int N2, int nx2) {
  __shared__ float tile[64][65];
  const int blk = blockIdx.x, tid = threadIdx.x;
  const float* W;
  f16* WT;
  int K, N, nx, local;
  if (blk < s1) { W = W0; WT = T0; K = K0; N = N0; nx = nx0; local = blk; }
  else if (blk < s2) { W = W1p; WT = T1; K = K1; N = N1; nx = nx1; local = blk - s1; }
  else { W = W2p; WT = T2; K = K2; N = N2; nx = nx2; local = blk - s2; }
  const int n0 = (local % nx) * 64, k0 = (local / nx) * 64;
  const int tn = tid & 63, tk4 = tid >> 6;
#pragma unroll
  for (int p = 0; p < 16; ++p) {
    const int kk = tk4 + p * 4;
    tile[kk][tn] = W[(size_t)(k0 + kk) * N + n0 + tn];
  }
  __syncthreads();
#pragma unroll
  for (int p = 0; p < 16; ++p) {
    const int nn = tk4 + p * 4;
    WT[(size_t)(n0 + nn) * K + k0 + tn] = (f16)tile[tn][nn];
  }
}

// ---------------- fp16 MFMA GEMM: C = A[M,K] * BT[N,K]^T ----------------
// R10: BM=64 gets a DEPTH-2 pipeline (3 LDS buffers, 36KB, still 4
// blocks/CU): counted vmcnt(3) leaves tile t+1's loads in flight across
// the barrier, so each load has ~2 step-times to land (was: 1 MFMA
// cluster). BM=128 keeps proven 2-buf depth-1 (3-buf would cost a block).
template <typename TC, int BM>
__global__ __launch_bounds__(256, 4) void hgemm_kernel(
    const f16* __restrict__ A, const f16* __restrict__ BT, TC* C,
    int N, int K, const float* __restrict__ bias, int relu,
    const f16* __restrict__ Aalt, TC* Calt, int split,
    TC* Cb, TC* Cbalt, int ksplit) {
  constexpr int MR = BM / 32;           // per-wave M-fragment repeats
  constexpr int NBUF = (BM == 64) ? 3 : 2;
  constexpr int DEPTH = NBUF - 1;       // tiles in flight
  __shared__ __align__(16) f16 sA[NBUF][BM * 32];
  __shared__ __align__(16) f16 sB[NBUF][128 * 32];
  const int tid = threadIdx.x;
  const int w = tid >> 6, lane = tid & 63;
  const int quad = lane >> 4, m16 = lane & 15;
  const int wr = w >> 1, wc = w & 1;
  // XCD-aware swizzle: all our grids have nwg % 8 == 0 (bijective).
  const int gx = gridDim.x;
  const int nwg = gx * gridDim.y;
  const int lin = blockIdx.y * gx + blockIdx.x;
  const int cpx = nwg >> 3;
  const int swz = (lin & 7) * cpx + (lin >> 3);
  const int bx = swz % gx;
  int by = swz / gx;
  int koff = 0, Kloc = K;
  if (ksplit == 2) {
    const int mh = gridDim.y >> 1;
    if (by >= mh) { by -= mh; koff = K >> 1; C = Cb; Calt = Cbalt; }
    Kloc = K >> 1;
  }
  const int col0 = bx * 128;
  int r0 = by * BM;
  const f16* Ause = A;
  TC* Cuse = C;
  if (r0 >= split) { Ause = Aalt; Cuse = Calt; r0 -= split; }

  // staging: thread t covers LDS row (t>>2) (+64 for BM=128's 2nd A gload
  // and B's 2nd gload), chunk t&3; fetches global chunk (t&3)^((row>>1)&3)
  const int strow = tid >> 2;
  const int schunk = tid & 3;
  const int sw = schunk ^ ((strow >> 1) & 3);
  const f16* gA0 = Ause + (size_t)(r0 + strow) * K + koff + sw * 8;
  const f16* gB0 = BT + (size_t)(col0 + strow) * K + koff + sw * 8;
  f16* ldsA0 = &sA[0][0] + (size_t)w * 512;
  f16* ldsB0 = &sB[0][0] + (size_t)w * 512;

  // ds_read offsets (f16 elems): row rt, swizzled chunk quad^((rt>>1)&3)
  const int qs = quad ^ ((m16 >> 1) & 3);
  int aoff[MR], boff[4];
#pragma unroll
  for (int i = 0; i < MR; ++i)
    aoff[i] = (wr * (BM / 2) + i * 16 + m16) * 32 + qs * 8;
#pragma unroll
  for (int i = 0; i < 4; ++i)
    boff[i] = (wc * 64 + i * 16 + m16) * 32 + qs * 8;

  const int nkt = Kloc >> 5;  // >= 16 in all our launches
  f32x4 acc[MR][4] = {};

  auto stage = [&](int buf, int t) {
    const int k0 = t << 5;
    const size_t bufoA = (size_t)buf * (BM * 32);
    const size_t bufoB = (size_t)buf * 4096;
    gload16(gA0 + k0, ldsA0 + bufoA);
    if constexpr (BM == 128)
      gload16(gA0 + (size_t)64 * K + k0, ldsA0 + bufoA + 2048);
    gload16(gB0 + k0, ldsB0 + bufoB);
    gload16(gB0 + (size_t)64 * K + k0, ldsB0 + bufoB + 2048);
  };

  // prologue: DEPTH tiles in flight
#pragma unroll
  for (int d = 0; d < DEPTH; ++d) stage(d, d);
  int cur = 0;
  for (int t = 0; t < nkt; ++t) {
    // tile t's loads are the oldest outstanding. DEPTH=2: leave tile
    // t+1's 3 loads in flight (vmcnt(3)); DEPTH=1: drain (vmcnt(0)).
    if constexpr (DEPTH == 2) {
      if (t + 1 < nkt) {
        asm volatile("s_waitcnt vmcnt(3)" ::: "memory");
      } else {
        asm volatile("s_waitcnt vmcnt(0)" ::: "memory");
      }
    } else {
      asm volatile("s_waitcnt vmcnt(0)" ::: "memory");
    }
    __builtin_amdgcn_s_barrier();  // all waves' tile-t loads visible
    if (t + DEPTH < nkt) {
      int nb = cur + DEPTH;
      if (nb >= NBUF) nb -= NBUF;
      stage(nb, t + DEPTH);  // slot read at t-1; all waves past that read
    }
    f16x8 af[MR], bfr[4];
#pragma unroll
    for (int i = 0; i < MR; ++i) af[i] = *(const f16x8*)&sA[cur][aoff[i]];
#pragma unroll
    for (int i = 0; i < 4; ++i) bfr[i] = *(const f16x8*)&sB[cur][boff[i]];
    __builtin_amdgcn_s_setprio(1);
#pragma unroll
    for (int mi = 0; mi < MR; ++mi)
#pragma unroll
      for (int ni = 0; ni < 4; ++ni)
        acc[mi][ni] = __builtin_amdgcn_mfma_f32_16x16x32_f16(
            af[mi], bfr[ni], acc[mi][ni], 0, 0, 0);
    __builtin_amdgcn_s_setprio(0);
    cur = (cur + 1 == NBUF) ? 0 : cur + 1;
  }

  // Epilogue: D layout col=lane&15, row=quad*4+rg (16x16 family)
#pragma unroll
  for (int mi = 0; mi < MR; ++mi) {
    const int row = r0 + wr * (BM / 2) + mi * 16 + quad * 4;
#pragma unroll
    for (int ni = 0; ni < 4; ++ni) {
      const int col = col0 + wc * 64 + ni * 16 + m16;
      const float bv = bias ? bias[col] : 0.f;
#pragma unroll
      for (int rg = 0; rg < 4; ++rg) {
        float vv = acc[mi][ni][rg] + bv;
        if (relu) vv = vv > 0.f ? vv : 0.f;
        store_c(&Cuse[(size_t)(row + rg) * N + col], vv);
      }
    }
  }
}

// ---------------- Fused flash-MFMA attention (unchanged from R8) ----------------
__global__ __launch_bounds__(256, 4) void fattn_kernel(
    const bf16* __restrict__ qkvp,  // [1536*4, 3072] rows k*B+b, bf16
    const bf16* __restrict__ rhp,   // [1536, 1024] bf16
    const float* __restrict__ u, const float* __restrict__ v,
    f16* __restrict__ ctxh) {       // [4096, 1024] f16
  const int lin = blockIdx.x;      // 1024 blocks
  const int p = lin & 63;          // (b,h) pair; p%8 = XCD
  const int b = p & 3, h = p >> 2;
  // magic square: residue classes {k, k+4, k+8, k+12} all sum to 30
  const int permv[16] = {15, 14, 13, 12, 10, 11, 8, 9, 4, 5, 6, 7, 1, 0, 3, 2};
  const int i0 = permv[lin >> 6] * 64;
  const int tid = threadIdx.x;
  const int w = tid >> 6, lane = tid & 63;
  const int quad = lane >> 4, m16 = lane & 15;

  __shared__ short sVt[64 * 40];   // V^T tile: [d][j]
  __shared__ short sR[96 * 72];    // R ring buffer (phys = (32kt+trel)%96)
  __shared__ short sProb[64 * 40]; // probs bf16, per-wave strips

  const short* qkv = (const short*)qkvp;
  const short* rh  = (const short*)rhp;

  // Per-lane Q fragments: aQu = q+u (AC), aQv = q+v (BD). Rows w*16+m16.
  short8 aQu0, aQu1, aQv0, aQv1;
  {
    const size_t qro = ((size_t)(512 + i0 + w * 16 + m16) * 4 + b) * 3072 + h * 64 + quad * 8;
    short8 qa = *(const short8*)&qkv[qro];
    short8 qb = *(const short8*)&qkv[qro + 32];
    const float* up = u + h * 64 + quad * 8;
    const float* vp = v + h * 64 + quad * 8;
#pragma unroll
    for (int j = 0; j < 8; ++j) {
      const float qaf = b2f(qa[j]), qbf = b2f(qb[j]);
      aQu0[j] = f2b(qaf + up[j]);
      aQu1[j] = f2b(qbf + up[j + 32]);
      aQv0[j] = f2b(qaf + vp[j]);
      aQv1[j] = f2b(qbf + vp[j + 32]);
    }
  }

  // staging maps
  const int st_row = tid >> 3, st_d0 = (tid & 7) * 8;        // R chunk (32 rows)
  const int vj = lane & 31, vd0 = w * 16 + (lane >> 5) * 8;  // V^T scatter

  // Initial R window fill: trel 0..95, t = 960-i0+trel (never negative)
#pragma unroll
  for (int p_ = 0; p_ < 3; ++p_) {
    int t = 960 - i0 + p_ * 32 + st_row;
    t = t > 1535 ? 1535 : t;  // clamped rows only feed masked elems
    *(short8*)&sR[(p_ * 32 + st_row) * 72 + st_d0] =
        *(const short8*)&rh[(size_t)t * 1024 + h * 64 + st_d0];
  }
  // V tile 0 scatter
  {
    short8 v8 = *(const short8*)&qkv[((size_t)vj * 4 + b) * 3072 + 2048 + h * 64 + vd0];
#pragma unroll
    for (int q = 0; q < 8; ++q) sVt[(vd0 + q) * 40 + vj] = v8[q];
  }
  // K fragments tile 0 (per-lane, direct from global)
  short8 rKf[4];
#pragma unroll
  for (int n0i = 0; n0i < 2; ++n0i) {
    const size_t kro = ((size_t)(n0i * 16 + m16) * 4 + b) * 3072 + 1024 + h * 64 + quad * 8;
    rKf[n0i * 2] = *(const short8*)&qkv[kro];
    rKf[n0i * 2 + 1] = *(const short8*)&qkv[kro + 32];
  }

  short8 ones;
#pragma unroll
  for (int q = 0; q < 8; ++q) ones[q] = (short)0x3F80;  // bf16 1.0

  f32x4 O[4] = {};
  f32x4 L = {};
  float m = -1e30f;
  int bk = 0;               // (32*kt) % 96: ring base; also write slot base
  int tnext = 1056 - i0;    // t-base of chunk staged for tile kt+1

  const int n_kt = ((i0 + 575) >> 5) + 1;  // valid j <= i+512, i <= i0+63
  for (int kt = 0; kt < n_kt; ++kt) {
    const int j0 = kt * 32;
    const bool pf = (kt + 1 < n_kt);
    __syncthreads();  // staged LDS writes visible

    // prefetch next tile: V + new R chunk into regs (latency hidden)
    short8 nV, nR;
    if (pf) {
      nV = *(const short8*)&qkv[((size_t)(j0 + 32 + vj) * 4 + b) * 3072 + 2048 + h * 64 + vd0];
      int t = tnext + st_row;
      t = t > 1535 ? 1535 : t;
      nR = *(const short8*)&rh[(size_t)t * 1024 + h * 64 + st_d0];
    }

    // AC tiles from register K fragments
    f32x4 ac[2];
#pragma unroll
    for (int n0i = 0; n0i < 2; ++n0i) {
      f32x4 a = {};
      a = __builtin_amdgcn_mfma_f32_16x16x32_bf16(aQu0, rKf[n0i * 2], a, 0, 0, 0);
      a = __builtin_amdgcn_mfma_f32_16x16x32_bf16(aQu1, rKf[n0i * 2 + 1], a, 0, 0, 0);
      ac[n0i] = a;
    }
    // prefetch next K fragments (regs free after AC)
    if (pf) {
#pragma unroll
      for (int n0i = 0; n0i < 2; ++n0i) {
        const size_t kro = ((size_t)(j0 + 32 + n0i * 16 + m16) * 4 + b) * 3072 + 1024 + h * 64 + quad * 8;
        rKf[n0i * 2] = *(const short8*)&qkv[kro];
        rKf[n0i * 2 + 1] = *(const short8*)&qkv[kro + 32];
      }
    }

    // P = Qv.R tiles (ring rows), wave trel window [48-16w, 94-16w]
    f32x4 pb[3];
#pragma unroll
    for (int pt = 0; pt < 3; ++pt) {
      const int p0 = 48 - 16 * w + 16 * pt;
      int pr = bk + p0;
      if (pr >= 96) pr -= 96;
      int row = pr + m16;
      if (row >= 96) row -= 96;
      const short8 bR0 = *(const short8*)&sR[row * 72 + quad * 8];
      const short8 bR1 = *(const short8*)&sR[row * 72 + 32 + quad * 8];
      f32x4 pf_ = {};
      pf_ = __builtin_amdgcn_mfma_f32_16x16x32_bf16(aQv0, bR0, pf_, 0, 0, 0);
      pf_ = __builtin_amdgcn_mfma_f32_16x16x32_bf16(aQv1, bR1, pf_, 0, 0, 0);
      pb[pt] = pf_;
    }

    // Scores; rel-shift P gather via in-wave shuffles (same quad, same rg)
    float S0[4], S1[4];
    float mxl = -1e30f;
#pragma unroll
    for (int rg = 0; rg < 4; ++rg) {
      const int rloc = quad * 4 + rg;
      const int irow = i0 + w * 16 + rloc;
      const int c0 = m16 - rloc + 15;  // in [0,30]
      const int src = (lane & 48) | (c0 & 15);
      const float t0 = __shfl(pb[0][rg], src);
      const float t1 = __shfl(pb[1][rg], src);
      const float t2 = __shfl(pb[2][rg], src);
      const float p0v = (c0 < 16) ? t0 : t1;
      const float p1v = (c0 < 16) ? t1 : t2;
      float s0 = (ac[0][rg] + p0v) * 0.125f;
      float s1 = (ac[1][rg] + p1v) * 0.125f;
      if (j0 + m16 > irow + 512) s0 = -1e30f;
      if (j0 + 16 + m16 > irow + 512) s1 = -1e30f;
      S0[rg] = s0;
      S1[rg] = s1;
      mxl = fmaxf(mxl, fmaxf(s0, s1));
    }
    // wave-shared max (valid upper bound for all 16 rows of this wave)
    mxl = fmaxf(mxl, __shfl_xor(mxl, 1));
    mxl = fmaxf(mxl, __shfl_xor(mxl, 2));
    mxl = fmaxf(mxl, __shfl_xor(mxl, 4));
    mxl = fmaxf(mxl, __shfl_xor(mxl, 8));
    mxl = fmaxf(mxl, __shfl_xor(mxl, 16));
    mxl = fmaxf(mxl, __shfl_xor(mxl, 32));
    // defer-max (T13): rescale only when max grew materially (wave-uniform)
    if (mxl > m + 8.f) {
      const float al = __expf(m - mxl);
      m = mxl;
#pragma unroll
      for (int d0i = 0; d0i < 4; ++d0i)
#pragma unroll
        for (int rg = 0; rg < 4; ++rg) O[d0i][rg] *= al;
#pragma unroll
      for (int rg = 0; rg < 4; ++rg) L[rg] *= al;
    }
#pragma unroll
    for (int rg = 0; rg < 4; ++rg) {
      const int rloc = quad * 4 + rg;
      const float e0 = __expf(S0[rg] - m);
      const float e1 = __expf(S1[rg] - m);
      unsigned pk;
      asm("v_cvt_pk_bf16_f32 %0, %1, %2" : "=v"(pk) : "v"(e0), "v"(e1));
      sProb[(w * 16 + rloc) * 40 + m16] = (short)(pk & 0xffff);
      sProb[(w * 16 + rloc) * 40 + 16 + m16] = (short)(pk >> 16);
    }

    // PV + row-sum accumulation (ones B-fragment broadcasts l to all cols)
    const short8 aP = *(const short8*)&sProb[(w * 16 + m16) * 40 + quad * 8];
    L = __builtin_amdgcn_mfma_f32_16x16x32_bf16(aP, ones, L, 0, 0, 0);
#pragma unroll
    for (int d0i = 0; d0i < 4; ++d0i) {
      const short8 bV = *(const short8*)&sVt[(d0i * 16 + m16) * 40 + quad * 8];
      O[d0i] = __builtin_amdgcn_mfma_f32_16x16x32_bf16(aP, bV, O[d0i], 0, 0, 0);
    }

    __syncthreads();  // all LDS reads done before restage
    if (pf) {
#pragma unroll
      for (int q = 0; q < 8; ++q) sVt[(vd0 + q) * 40 + vj] = nV[q];
      *(short8*)&sR[(bk + st_row) * 72 + st_d0] = nR;  // new chunk slot
    }
    bk += 32;
    if (bk >= 96) bk = 0;
    tnext += 32;
  }

  // Epilogue: ctxh[i*B+b][h*64+d] = (f16)(O/L)
#pragma unroll
  for (int d0i = 0; d0i < 4; ++d0i) {
#pragma unroll
    for (int rg = 0; rg < 4; ++rg) {
      const int irow = i0 + w * 16 + quad * 4 + rg;
      ctxh[((size_t)irow * 4 + b) * 1024 + h * 64 + d0i * 16 + m16] =
          (f16)(O[d0i][rg] / L[rg]);
    }
  }
}

// ---------------- LayerNorms ----------------
// ln1: x = LN(ya + yb + inputs); emits f16 x_h only.
__global__ __launch_bounds__(256) void ln1_kernel(
    const f16* __restrict__ ya, const f16* __restrict__ yb,
    const float* __restrict__ inp, const float* __restrict__ g,
    const float* __restrict__ beta, f16* __restrict__ xh) {
  const int r = blockIdx.x, tid = threadIdx.x;
  __shared__ float red[256];
  float t[4];
  float s = 0.f;
#pragma unroll
  for (int q = 0; q < 4; ++q) {
    int c = tid + q * 256;
    t[q] = (float)ya[(size_t)r * DM + c] + (float)yb[(size_t)r * DM + c] +
           inp[(size_t)r * DM + c];
    s += t[q];
  }
  red[tid] = s;
  __syncthreads();
  for (int st = 128; st > 0; st >>= 1) {
    if (tid < st) red[tid] += red[tid + st];
    __syncthreads();
  }
  const float mean = red[0] * (1.f / DM);
  __syncthreads();
  float vs = 0.f;
#pragma unroll
  for (int q = 0; q < 4; ++q) {
    float d0 = t[q] - mean;
    vs += d0 * d0;
  }
  red[tid] = vs;
  __syncthreads();
  for (int st = 128; st > 0; st >>= 1) {
    if (tid < st) red[tid] += red[tid + st];
    __syncthreads();
  }
  const float rstd = rsqrtf(red[0] * (1.f / DM) + 1e-5f);
#pragma unroll
  for (int q = 0; q < 4; ++q) {
    int c = tid + q * 256;
    const float val = (t[q] - mean) * rstd * g[c] + beta[c];
    xh[(size_t)r * DM + c] = (f16)val;
  }
}

// ln2: out = LN(x_h + y2a + y2b + b2), fp32 out.
__global__ __launch_bounds__(256) void ln2_kernel(
    const f16* __restrict__ xh, const f16* __restrict__ y2a,
    const f16* __restrict__ y2b, const float* __restrict__ b2,
    const float* __restrict__ g, const float* __restrict__ beta,
    float* __restrict__ out) {
  const int r = blockIdx.x, tid = threadIdx.x;
  __shared__ float red[256];
  float t[4];
  float s = 0.f;
#pragma unroll
  for (int q = 0; q < 4; ++q) {
    int c = tid + q * 256;
    t[q] = (float)xh[(size_t)r * DM + c] + (float)y2a[(size_t)r * DM + c] +
           (float)y2b[(size_t)r * DM + c] + b2[c];
    s += t[q];
  }
  red[tid] = s;
  __syncthreads();
  for (int st = 128; st > 0; st >>= 1) {
    if (tid < st) red[tid] += red[tid + st];
    __syncthreads();
  }
  const float mean = red[0] * (1.f / DM);
  __syncthreads();
  float vs = 0.f;
#pragma unroll
  for (int q = 0; q < 4; ++q) {
    float d0 = t[q] - mean;
    vs += d0 * d0;
  }
  red[tid] = vs;
  __syncthreads();
  for (int st = 128; st > 0; st >>= 1) {
    if (tid < st) red[tid] += red[tid + st];
    __syncthreads();
  }
  const float rstd = rsqrtf(red[0] * (1.f / DM) + 1e-5f);
#pragma unroll
  for (int q = 0; q < 4; ++q) {
    int c = tid + q * 256;
    out[(size_t)r * DM + c] = (t[q] - mean) * rstd * g[c] + beta[c];
  }
}

extern "C" void kernel_launch(void* const* d_in, const int* in_sizes, int n_in,
                              void* d_out, int out_size, void* d_ws, size_t ws_size,
                              hipStream_t stream) {
  const int o = (n_in >= 17) ? 1 : 0;
  const float* inputs = (const float*)d_in[0];
  const float* r      = (const float*)d_in[1];
  const float* u      = (const float*)d_in[2];
  const float* v      = (const float*)d_in[3];
  const float* memp   = (const float*)d_in[4];
  const float* W_qkv  = (const float*)d_in[5 + o];
  const float* W_r    = (const float*)d_in[6 + o];
  const float* W_o    = (const float*)d_in[7 + o];
  const float* ln1_g  = (const float*)d_in[8 + o];
  const float* ln1_b  = (const float*)d_in[9 + o];
  const float* ln2_g  = (const float*)d_in[10 + o];
  const float* ln2_b  = (const float*)d_in[11 + o];
  const float* W1     = (const float*)d_in[12 + o];
  const float* b1     = (const float*)d_in[13 + o];
  const float* W2     = (const float*)d_in[14 + o];
  const float* b2     = (const float*)d_in[15 + o];

  // Workspace liveness (peak 52,428,800 B) — unchanged from R7/R8/R9
  char* ws = (char*)d_ws;
  f16*  WqkvT = (f16*)(ws);
  f16*  r16   = (f16*)(ws + 6291456);
  f16*  WrT   = (f16*)(ws + 9437184);
  bf16* qkv   = (bf16*)(ws + 11534336);
  bf16* rh    = (bf16*)(ws + 49283072);
  f16*  cat_h = (f16*)d_out;
  f16*  ctx_h = (f16*)(ws);
  f16*  WoT   = (f16*)(ws + 8388608);
  f16*  ya    = (f16*)(ws + 10485760);
  f16*  yb    = (f16*)(ws + 18874368);
  f16*  x_h   = (f16*)(ws + 27262976);
  f16*  W1T   = (f16*)(ws + 35651584);
  f16*  h_hi  = (f16*)(ws);
  f16*  h_lo  = (f16*)d_out;
  f16*  W2T   = (f16*)(ws + 44040192);
  f16*  y2a   = (f16*)(ws + 18874368);
  f16*  y2b   = (f16*)(ws + 35651584);

  dim3 blk(256);
  const int BIG = 1 << 30;

  // --- phase 1: converts + QKV/R projections + attention ---
  convh3_kernel<<<dim3(7680), blk, 0, stream>>>(
      memp, inputs, r, cat_h, cat_h + (size_t)2048 * 1024, r16);
  convTm_kernel<<<dim3(1024), blk, 0, stream>>>(
      W_qkv, WqkvT, 1024, 3072, 48,
      768, W_r, WrT, 1024, 1024, 16,
      1024, nullptr, nullptr, 0, 0, 1);
  // QKV split: mem rows (0..2047) only need k,v cols [1024,3072) — BM=64
  // depth-2; input rows (2048..6143) all cols — BM=128 depth-1.
  hgemm_kernel<bf16, 64><<<dim3(16, 32), blk, 0, stream>>>(
      cat_h, WqkvT + (size_t)1024 * 1024, qkv + 1024, 3072, 1024, nullptr, 0,
      nullptr, nullptr, BIG, nullptr, nullptr, 1);
  hgemm_kernel<bf16, 128><<<dim3(24, 32), blk, 0, stream>>>(
      cat_h + (size_t)2048 * 1024, WqkvT, qkv + (size_t)2048 * 3072,
      3072, 1024, nullptr, 0,
      nullptr, nullptr, BIG, nullptr, nullptr, 1);
  hgemm_kernel<bf16, 64><<<dim3(8, 24), blk, 0, stream>>>(
      r16, WrT, rh, 1024, 1024, nullptr, 0,
      nullptr, nullptr, BIG, nullptr, nullptr, 1);
  fattn_kernel<<<dim3(1024), blk, 0, stream>>>(qkv, rh, u, v, ctx_h);

  // --- phase 2: weight transposes + output proj + LN1 + MLP + LN2 ---
  convTm_kernel<<<dim3(2304), blk, 0, stream>>>(
      W_o, WoT, 1024, 1024, 16,
      256, W1, W1T, 1024, 4096, 64,
      1280, W2, W2T, 4096, 1024, 16);
  hgemm_kernel<f16, 64><<<dim3(8, 128), blk, 0, stream>>>(
      ctx_h, WoT, ya, 1024, 1024, nullptr, 0,
      nullptr, nullptr, BIG, yb, nullptr, 2);
  ln1_kernel<<<dim3(4096), blk, 0, stream>>>(ya, yb, inputs, ln1_g, ln1_b, x_h);
  hgemm_kernel<f16, 128><<<dim3(32, 32), blk, 0, stream>>>(
      x_h, W1T, h_lo, 4096, 1024, b1, 1,
      x_h + (size_t)2048 * 1024, h_hi, 2048, nullptr, nullptr, 1);
  hgemm_kernel<f16, 64><<<dim3(8, 128), blk, 0, stream>>>(
      h_lo, W2T, y2a, 1024, 4096, nullptr, 0,
      h_hi, y2a + (size_t)2048 * 1024, 2048,
      y2b, y2b + (size_t)2048 * 1024, 2);
  ln2_kernel<<<dim3(4096), blk, 0, stream>>>(x_h, y2a, y2b, b2, ln2_g, ln2_b,
                                             (float*)d_out);
}

// Round 11
// 436.167 us; speedup vs baseline: 1.0412x; 1.0412x over previous
//
#include <hip/hip_runtime.h>
#include <hip/hip_bf16.h>

typedef __hip_bfloat16 bf16;
typedef _Float16 f16;
typedef __attribute__((ext_vector_type(8))) short short8;
typedef __attribute__((ext_vector_type(4))) float f32x4;
typedef __attribute__((ext_vector_type(8))) _Float16 f16x8;
typedef __attribute__((ext_vector_type(4))) _Float16 f16x4;

#define Q_LEN 1024
#define B_SZ 4
#define DM 1024
#define H_CNT 16
#define HD 64
#define MEM_LEN 512
#define KLEN 1536
#define MLP 4096

__device__ __forceinline__ void store_c(float* p, float v) { *p = v; }
__device__ __forceinline__ void store_c(bf16* p, float v) { *p = __float2bfloat16(v); }
__device__ __forceinline__ void store_c(f16* p, float v) { *p = (f16)v; }

__device__ __forceinline__ float b2f(short s) {
  union { unsigned u; float f; } x;
  x.u = ((unsigned)(unsigned short)s) << 16;
  return x.f;
}
__device__ __forceinline__ short f2b(float f) {
  union { float f; unsigned u; } x;
  x.f = f;
  unsigned r = x.u + 0x7fff + ((x.u >> 16) & 1);  // RNE; inputs finite
  return (short)(r >> 16);
}

// async global->LDS, 16B per lane; LDS dest = wave-uniform base + lane*16
__device__ __forceinline__ void gload16(const void* g, void* l) {
  __builtin_amdgcn_global_load_lds(
      (__attribute__((address_space(1))) unsigned int*)(g),
      (__attribute__((address_space(3))) unsigned int*)(l), 16, 0, 0);
}

// ------- merged fp32 -> fp16 convert: 3 segments in one launch -------
__global__ __launch_bounds__(256) void convh3_kernel(
    const float* __restrict__ X0, const float* __restrict__ X1,
    const float* __restrict__ X2, f16* __restrict__ Y0,
    f16* __restrict__ Y1, f16* __restrict__ Y2) {
  const int blk = blockIdx.x, tid = threadIdx.x;
  const float* X;
  f16* Y;
  int i;
  if (blk < 2048) { X = X0; Y = Y0; i = blk * 256 + tid; }
  else if (blk < 6144) { X = X1; Y = Y1; i = (blk - 2048) * 256 + tid; }
  else { X = X2; Y = Y2; i = (blk - 6144) * 256 + tid; }
  f32x4 v = *(const f32x4*)&X[(size_t)i * 4];
  f16x4 h;
#pragma unroll
  for (int j = 0; j < 4; ++j) h[j] = (f16)v[j];
  *(f16x4*)&Y[(size_t)i * 4] = h;
}

// ------- merged fp32 [K][N] -> fp16 [N][K] transpose: 3 descriptors -------
__global__ __launch_bounds__(256) void convTm_kernel(
    const float* W0, f16* T0, int K0, int N0, int nx0,
    int s1, const float* W1p, f16* T1, int K1, int N1, int nx1,
    int s2, const float* W2p, f16* T2, int K2, int N2, int nx2) {
  __shared__ float tile[64][65];
  const int blk = blockIdx.x, tid = threadIdx.x;
  const float* W;
  f16* WT;
  int K, N, nx, local;
  if (blk < s1) { W = W0; WT = T0; K = K0; N = N0; nx = nx0; local = blk; }
  else if (blk < s2) { W = W1p; WT = T1; K = K1; N = N1; nx = nx1; local = blk - s1; }
  else { W = W2p; WT = T2; K = K2; N = N2; nx = nx2; local = blk - s2; }
  const int n0 = (local % nx) * 64, k0 = (local / nx) * 64;
  const int tn = tid & 63, tk4 = tid >> 6;
#pragma unroll
  for (int p = 0; p < 16; ++p) {
    const int kk = tk4 + p * 4;
    tile[kk][tn] = W[(size_t)(k0 + kk) * N + n0 + tn];
  }
  __syncthreads();
#pragma unroll
  for (int p = 0; p < 16; ++p) {
    const int nn = tk4 + p * 4;
    WT[(size_t)(n0 + nn) * K + k0 + tn] = (f16)tile[tn][nn];
  }
}

// ---------------- fp16 MFMA GEMM: C = A[M,K] * BT[N,K]^T ----------------
// R9 structure (numerically best): 2-buffer depth-1, BM template, split-K,
// XCD swizzle, 4 blocks/CU.
template <typename TC, int BM>
__global__ __launch_bounds__(256, 4) void hgemm_kernel(
    const f16* __restrict__ A, const f16* __restrict__ BT, TC* C,
    int N, int K, const float* __restrict__ bias, int relu,
    const f16* __restrict__ Aalt, TC* Calt, int split,
    TC* Cb, TC* Cbalt, int ksplit) {
  constexpr int MR = BM / 32;           // per-wave M-fragment repeats
  __shared__ __align__(16) f16 sA[2][BM * 32];
  __shared__ __align__(16) f16 sB[2][128 * 32];
  const int tid = threadIdx.x;
  const int w = tid >> 6, lane = tid & 63;
  const int quad = lane >> 4, m16 = lane & 15;
  const int wr = w >> 1, wc = w & 1;
  // XCD-aware swizzle: all our grids have nwg % 8 == 0 (bijective).
  const int gx = gridDim.x;
  const int nwg = gx * gridDim.y;
  const int lin = blockIdx.y * gx + blockIdx.x;
  const int cpx = nwg >> 3;
  const int swz = (lin & 7) * cpx + (lin >> 3);
  const int bx = swz % gx;
  int by = swz / gx;
  int koff = 0, Kloc = K;
  if (ksplit == 2) {
    const int mh = gridDim.y >> 1;
    if (by >= mh) { by -= mh; koff = K >> 1; C = Cb; Calt = Cbalt; }
    Kloc = K >> 1;
  }
  const int col0 = bx * 128;
  int r0 = by * BM;
  const f16* Ause = A;
  TC* Cuse = C;
  if (r0 >= split) { Ause = Aalt; Cuse = Calt; r0 -= split; }

  const int strow = tid >> 2;
  const int schunk = tid & 3;
  const int sw = schunk ^ ((strow >> 1) & 3);
  const f16* gA0 = Ause + (size_t)(r0 + strow) * K + koff + sw * 8;
  const f16* gB0 = BT + (size_t)(col0 + strow) * K + koff + sw * 8;
  f16* ldsA0 = &sA[0][0] + (size_t)w * 512;
  f16* ldsB0 = &sB[0][0] + (size_t)w * 512;

  const int qs = quad ^ ((m16 >> 1) & 3);
  int aoff[MR], boff[4];
#pragma unroll
  for (int i = 0; i < MR; ++i)
    aoff[i] = (wr * (BM / 2) + i * 16 + m16) * 32 + qs * 8;
#pragma unroll
  for (int i = 0; i < 4; ++i)
    boff[i] = (wc * 64 + i * 16 + m16) * 32 + qs * 8;

  const int nkt = Kloc >> 5;
  f32x4 acc[MR][4] = {};

  auto stage = [&](int buf, int t) {
    const int k0 = t << 5;
    const size_t bufoA = (size_t)buf * (BM * 32);
    const size_t bufoB = (size_t)buf * 4096;
    gload16(gA0 + k0, ldsA0 + bufoA);
    if constexpr (BM == 128)
      gload16(gA0 + (size_t)64 * K + k0, ldsA0 + bufoA + 2048);
    gload16(gB0 + k0, ldsB0 + bufoB);
    gload16(gB0 + (size_t)64 * K + k0, ldsB0 + bufoB + 2048);
  };

  stage(0, 0);
  int cur = 0;
  for (int t = 0; t < nkt; ++t) {
    asm volatile("s_waitcnt vmcnt(0)" ::: "memory");
    __builtin_amdgcn_s_barrier();
    if (t + 1 < nkt) stage(cur ^ 1, t + 1);
    f16x8 af[MR], bfr[4];
#pragma unroll
    for (int i = 0; i < MR; ++i) af[i] = *(const f16x8*)&sA[cur][aoff[i]];
#pragma unroll
    for (int i = 0; i < 4; ++i) bfr[i] = *(const f16x8*)&sB[cur][boff[i]];
    __builtin_amdgcn_s_setprio(1);
#pragma unroll
    for (int mi = 0; mi < MR; ++mi)
#pragma unroll
      for (int ni = 0; ni < 4; ++ni)
        acc[mi][ni] = __builtin_amdgcn_mfma_f32_16x16x32_f16(
            af[mi], bfr[ni], acc[mi][ni], 0, 0, 0);
    __builtin_amdgcn_s_setprio(0);
    cur ^= 1;
  }

#pragma unroll
  for (int mi = 0; mi < MR; ++mi) {
    const int row = r0 + wr * (BM / 2) + mi * 16 + quad * 4;
#pragma unroll
    for (int ni = 0; ni < 4; ++ni) {
      const int col = col0 + wc * 64 + ni * 16 + m16;
      const float bv = bias ? bias[col] : 0.f;
#pragma unroll
      for (int rg = 0; rg < 4; ++rg) {
        float vv = acc[mi][ni][rg] + bv;
        if (relu) vv = vv > 0.f ? vv : 0.f;
        store_c(&Cuse[(size_t)(row + rg) * N + col], vv);
      }
    }
  }
}

// ---- merged phase-1 GEMM: 3 descriptors, uniform BM=64, K=1024, bf16 out --
// desc selection by block range; per-desc XCD swizzle (all counts %8==0).
__global__ __launch_bounds__(256, 4) void hgemm3_kernel(
    const f16* __restrict__ A0, const f16* __restrict__ B0,
    bf16* __restrict__ C0, int N0, int gx0,
    int s1, const f16* __restrict__ A1, const f16* __restrict__ B1,
    bf16* __restrict__ C1, int N1, int gx1,
    int s2, const f16* __restrict__ A2, const f16* __restrict__ B2,
    bf16* __restrict__ C2, int N2, int gx2) {
  constexpr int K = 1024;
  __shared__ __align__(16) f16 sA[2][64 * 32];
  __shared__ __align__(16) f16 sB[2][128 * 32];
  const int blk = blockIdx.x, tid = threadIdx.x;
  const int w = tid >> 6, lane = tid & 63;
  const int quad = lane >> 4, m16 = lane & 15;
  const int wr = w >> 1, wc = w & 1;
  const f16 *A, *BT;
  bf16* C;
  int N, gx, local, cnt;
  if (blk < s1) { A = A0; BT = B0; C = C0; N = N0; gx = gx0; local = blk; cnt = s1; }
  else if (blk < s2) { A = A1; BT = B1; C = C1; N = N1; gx = gx1; local = blk - s1; cnt = s2 - s1; }
  else { A = A2; BT = B2; C = C2; N = N2; gx = gx2; local = blk - s2; cnt = (int)gridDim.x - s2; }
  const int cpx = cnt >> 3;
  const int swz = (local & 7) * cpx + (local >> 3);
  const int bx = swz % gx, by = swz / gx;
  const int col0 = bx * 128;
  const int r0 = by * 64;

  const int strow = tid >> 2;
  const int schunk = tid & 3;
  const int sw = schunk ^ ((strow >> 1) & 3);
  const f16* gA0 = A + (size_t)(r0 + strow) * K + sw * 8;
  const f16* gB0 = BT + (size_t)(col0 + strow) * K + sw * 8;
  f16* ldsA0 = &sA[0][0] + (size_t)w * 512;
  f16* ldsB0 = &sB[0][0] + (size_t)w * 512;

  const int qs = quad ^ ((m16 >> 1) & 3);
  int aoff[2], boff[4];
#pragma unroll
  for (int i = 0; i < 2; ++i)
    aoff[i] = (wr * 32 + i * 16 + m16) * 32 + qs * 8;
#pragma unroll
  for (int i = 0; i < 4; ++i)
    boff[i] = (wc * 64 + i * 16 + m16) * 32 + qs * 8;

  f32x4 acc[2][4] = {};

  auto stage = [&](int buf, int t) {
    const int k0 = t << 5;
    const size_t bufoA = (size_t)buf * 2048;
    const size_t bufoB = (size_t)buf * 4096;
    gload16(gA0 + k0, ldsA0 + bufoA);
    gload16(gB0 + k0, ldsB0 + bufoB);
    gload16(gB0 + (size_t)64 * K + k0, ldsB0 + bufoB + 2048);
  };

  stage(0, 0);
  int cur = 0;
  for (int t = 0; t < 32; ++t) {
    asm volatile("s_waitcnt vmcnt(0)" ::: "memory");
    __builtin_amdgcn_s_barrier();
    if (t + 1 < 32) stage(cur ^ 1, t + 1);
    f16x8 af[2], bfr[4];
#pragma unroll
    for (int i = 0; i < 2; ++i) af[i] = *(const f16x8*)&sA[cur][aoff[i]];
#pragma unroll
    for (int i = 0; i < 4; ++i) bfr[i] = *(const f16x8*)&sB[cur][boff[i]];
    __builtin_amdgcn_s_setprio(1);
#pragma unroll
    for (int mi = 0; mi < 2; ++mi)
#pragma unroll
      for (int ni = 0; ni < 4; ++ni)
        acc[mi][ni] = __builtin_amdgcn_mfma_f32_16x16x32_f16(
            af[mi], bfr[ni], acc[mi][ni], 0, 0, 0);
    __builtin_amdgcn_s_setprio(0);
    cur ^= 1;
  }

#pragma unroll
  for (int mi = 0; mi < 2; ++mi) {
    const int row = r0 + wr * 32 + mi * 16 + quad * 4;
#pragma unroll
    for (int ni = 0; ni < 4; ++ni) {
      const int col = col0 + wc * 64 + ni * 16 + m16;
#pragma unroll
      for (int rg = 0; rg < 4; ++rg)
        C[(size_t)(row + rg) * N + col] = __float2bfloat16(acc[mi][ni][rg]);
    }
  }
}

// ---------------- Fused flash-MFMA attention (unchanged from R8/R9) --------
__global__ __launch_bounds__(256, 4) void fattn_kernel(
    const bf16* __restrict__ qkvp,  // [1536*4, 3072] rows k*B+b, bf16
    const bf16* __restrict__ rhp,   // [1536, 1024] bf16
    const float* __restrict__ u, const float* __restrict__ v,
    f16* __restrict__ ctxh) {       // [4096, 1024] f16
  const int lin = blockIdx.x;      // 1024 blocks
  const int p = lin & 63;          // (b,h) pair; p%8 = XCD
  const int b = p & 3, h = p >> 2;
  // magic square: residue classes {k, k+4, k+8, k+12} all sum to 30
  const int permv[16] = {15, 14, 13, 12, 10, 11, 8, 9, 4, 5, 6, 7, 1, 0, 3, 2};
  const int i0 = permv[lin >> 6] * 64;
  const int tid = threadIdx.x;
  const int w = tid >> 6, lane = tid & 63;
  const int quad = lane >> 4, m16 = lane & 15;

  __shared__ short sVt[64 * 40];   // V^T tile: [d][j]
  __shared__ short sR[96 * 72];    // R ring buffer (phys = (32kt+trel)%96)
  __shared__ short sProb[64 * 40]; // probs bf16, per-wave strips

  const short* qkv = (const short*)qkvp;
  const short* rh  = (const short*)rhp;

  // Per-lane Q fragments: aQu = q+u (AC), aQv = q+v (BD). Rows w*16+m16.
  short8 aQu0, aQu1, aQv0, aQv1;
  {
    const size_t qro = ((size_t)(512 + i0 + w * 16 + m16) * 4 + b) * 3072 + h * 64 + quad * 8;
    short8 qa = *(const short8*)&qkv[qro];
    short8 qb = *(const short8*)&qkv[qro + 32];
    const float* up = u + h * 64 + quad * 8;
    const float* vp = v + h * 64 + quad * 8;
#pragma unroll
    for (int j = 0; j < 8; ++j) {
      const float qaf = b2f(qa[j]), qbf = b2f(qb[j]);
      aQu0[j] = f2b(qaf + up[j]);
      aQu1[j] = f2b(qbf + up[j + 32]);
      aQv0[j] = f2b(qaf + vp[j]);
      aQv1[j] = f2b(qbf + vp[j + 32]);
    }
  }

  // staging maps
  const int st_row = tid >> 3, st_d0 = (tid & 7) * 8;        // R chunk (32 rows)
  const int vj = lane & 31, vd0 = w * 16 + (lane >> 5) * 8;  // V^T scatter

  // Initial R window fill: trel 0..95, t = 960-i0+trel (never negative)
#pragma unroll
  for (int p_ = 0; p_ < 3; ++p_) {
    int t = 960 - i0 + p_ * 32 + st_row;
    t = t > 1535 ? 1535 : t;  // clamped rows only feed masked elems
    *(short8*)&sR[(p_ * 32 + st_row) * 72 + st_d0] =
        *(const short8*)&rh[(size_t)t * 1024 + h * 64 + st_d0];
  }
  // V tile 0 scatter
  {
    short8 v8 = *(const short8*)&qkv[((size_t)vj * 4 + b) * 3072 + 2048 + h * 64 + vd0];
#pragma unroll
    for (int q = 0; q < 8; ++q) sVt[(vd0 + q) * 40 + vj] = v8[q];
  }
  // K fragments tile 0 (per-lane, direct from global)
  short8 rKf[4];
#pragma unroll
  for (int n0i = 0; n0i < 2; ++n0i) {
    const size_t kro = ((size_t)(n0i * 16 + m16) * 4 + b) * 3072 + 1024 + h * 64 + quad * 8;
    rKf[n0i * 2] = *(const short8*)&qkv[kro];
    rKf[n0i * 2 + 1] = *(const short8*)&qkv[kro + 32];
  }

  short8 ones;
#pragma unroll
  for (int q = 0; q < 8; ++q) ones[q] = (short)0x3F80;  // bf16 1.0

  f32x4 O[4] = {};
  f32x4 L = {};
  float m = -1e30f;
  int bk = 0;               // (32*kt) % 96: ring base; also write slot base
  int tnext = 1056 - i0;    // t-base of chunk staged for tile kt+1

  const int n_kt = ((i0 + 575) >> 5) + 1;  // valid j <= i+512, i <= i0+63
  for (int kt = 0; kt < n_kt; ++kt) {
    const int j0 = kt * 32;
    const bool pf = (kt + 1 < n_kt);
    __syncthreads();  // staged LDS writes visible

    // prefetch next tile: V + new R chunk into regs (latency hidden)
    short8 nV, nR;
    if (pf) {
      nV = *(const short8*)&qkv[((size_t)(j0 + 32 + vj) * 4 + b) * 3072 + 2048 + h * 64 + vd0];
      int t = tnext + st_row;
      t = t > 1535 ? 1535 : t;
      nR = *(const short8*)&rh[(size_t)t * 1024 + h * 64 + st_d0];
    }

    // AC tiles from register K fragments
    f32x4 ac[2];
#pragma unroll
    for (int n0i = 0; n0i < 2; ++n0i) {
      f32x4 a = {};
      a = __builtin_amdgcn_mfma_f32_16x16x32_bf16(aQu0, rKf[n0i * 2], a, 0, 0, 0);
      a = __builtin_amdgcn_mfma_f32_16x16x32_bf16(aQu1, rKf[n0i * 2 + 1], a, 0, 0, 0);
      ac[n0i] = a;
    }
    // prefetch next K fragments (regs free after AC)
    if (pf) {
#pragma unroll
      for (int n0i = 0; n0i < 2; ++n0i) {
        const size_t kro = ((size_t)(j0 + 32 + n0i * 16 + m16) * 4 + b) * 3072 + 1024 + h * 64 + quad * 8;
        rKf[n0i * 2] = *(const short8*)&qkv[kro];
        rKf[n0i * 2 + 1] = *(const short8*)&qkv[kro + 32];
      }
    }

    // P = Qv.R tiles (ring rows), wave trel window [48-16w, 94-16w]
    f32x4 pb[3];
#pragma unroll
    for (int pt = 0; pt < 3; ++pt) {
      const int p0 = 48 - 16 * w + 16 * pt;
      int pr = bk + p0;
      if (pr >= 96) pr -= 96;
      int row = pr + m16;
      if (row >= 96) row -= 96;
      const short8 bR0 = *(const short8*)&sR[row * 72 + quad * 8];
      const short8 bR1 = *(const short8*)&sR[row * 72 + 32 + quad * 8];
      f32x4 pf_ = {};
      pf_ = __builtin_amdgcn_mfma_f32_16x16x32_bf16(aQv0, bR0, pf_, 0, 0, 0);
      pf_ = __builtin_amdgcn_mfma_f32_16x16x32_bf16(aQv1, bR1, pf_, 0, 0, 0);
      pb[pt] = pf_;
    }

    // Scores; rel-shift P gather via in-wave shuffles (same quad, same rg)
    float S0[4], S1[4];
    float mxl = -1e30f;
#pragma unroll
    for (int rg = 0; rg < 4; ++rg) {
      const int rloc = quad * 4 + rg;
      const int irow = i0 + w * 16 + rloc;
      const int c0 = m16 - rloc + 15;  // in [0,30]
      const int src = (lane & 48) | (c0 & 15);
      const float t0 = __shfl(pb[0][rg], src);
      const float t1 = __shfl(pb[1][rg], src);
      const float t2 = __shfl(pb[2][rg], src);
      const float p0v = (c0 < 16) ? t0 : t1;
      const float p1v = (c0 < 16) ? t1 : t2;
      float s0 = (ac[0][rg] + p0v) * 0.125f;
      float s1 = (ac[1][rg] + p1v) * 0.125f;
      if (j0 + m16 > irow + 512) s0 = -1e30f;
      if (j0 + 16 + m16 > irow + 512) s1 = -1e30f;
      S0[rg] = s0;
      S1[rg] = s1;
      mxl = fmaxf(mxl, fmaxf(s0, s1));
    }
    // wave-shared max (valid upper bound for all 16 rows of this wave)
    mxl = fmaxf(mxl, __shfl_xor(mxl, 1));
    mxl = fmaxf(mxl, __shfl_xor(mxl, 2));
    mxl = fmaxf(mxl, __shfl_xor(mxl, 4));
    mxl = fmaxf(mxl, __shfl_xor(mxl, 8));
    mxl = fmaxf(mxl, __shfl_xor(mxl, 16));
    mxl = fmaxf(mxl, __shfl_xor(mxl, 32));
    // defer-max (T13): rescale only when max grew materially (wave-uniform)
    if (mxl > m + 8.f) {
      const float al = __expf(m - mxl);
      m = mxl;
#pragma unroll
      for (int d0i = 0; d0i < 4; ++d0i)
#pragma unroll
        for (int rg = 0; rg < 4; ++rg) O[d0i][rg] *= al;
#pragma unroll
      for (int rg = 0; rg < 4; ++rg) L[rg] *= al;
    }
#pragma unroll
    for (int rg = 0; rg < 4; ++rg) {
      const int rloc = quad * 4 + rg;
      const float e0 = __expf(S0[rg] - m);
      const float e1 = __expf(S1[rg] - m);
      unsigned pk;
      asm("v_cvt_pk_bf16_f32 %0, %1, %2" : "=v"(pk) : "v"(e0), "v"(e1));
      sProb[(w * 16 + rloc) * 40 + m16] = (short)(pk & 0xffff);
      sProb[(w * 16 + rloc) * 40 + 16 + m16] = (short)(pk >> 16);
    }

    // PV + row-sum accumulation (ones B-fragment broadcasts l to all cols)
    const short8 aP = *(const short8*)&sProb[(w * 16 + m16) * 40 + quad * 8];
    L = __builtin_amdgcn_mfma_f32_16x16x32_bf16(aP, ones, L, 0, 0, 0);
#pragma unroll
    for (int d0i = 0; d0i < 4; ++d0i) {
      const short8 bV = *(const short8*)&sVt[(d0i * 16 + m16) * 40 + quad * 8];
      O[d0i] = __builtin_amdgcn_mfma_f32_16x16x32_bf16(aP, bV, O[d0i], 0, 0, 0);
    }

    __syncthreads();  // all LDS reads done before restage
    if (pf) {
#pragma unroll
      for (int q = 0; q < 8; ++q) sVt[(vd0 + q) * 40 + vj] = nV[q];
      *(short8*)&sR[(bk + st_row) * 72 + st_d0] = nR;  // new chunk slot
    }
    bk += 32;
    if (bk >= 96) bk = 0;
    tnext += 32;
  }

  // Epilogue: ctxh[i*B+b][h*64+d] = (f16)(O/L)
#pragma unroll
  for (int d0i = 0; d0i < 4; ++d0i) {
#pragma unroll
    for (int rg = 0; rg < 4; ++rg) {
      const int irow = i0 + w * 16 + quad * 4 + rg;
      ctxh[((size_t)irow * 4 + b) * 1024 + h * 64 + d0i * 16 + m16] =
          (f16)(O[d0i][rg] / L[rg]);
    }
  }
}

// ---------------- LayerNorms ----------------
// ln1: x = LN(ya + yb + inputs); emits f16 x_h only.
__global__ __launch_bounds__(256) void ln1_kernel(
    const f16* __restrict__ ya, const f16* __restrict__ yb,
    const float* __restrict__ inp, const float* __restrict__ g,
    const float* __restrict__ beta, f16* __restrict__ xh) {
  const int r = blockIdx.x, tid = threadIdx.x;
  __shared__ float red[256];
  float t[4];
  float s = 0.f;
#pragma unroll
  for (int q = 0; q < 4; ++q) {
    int c = tid + q * 256;
    t[q] = (float)ya[(size_t)r * DM + c] + (float)yb[(size_t)r * DM + c] +
           inp[(size_t)r * DM + c];
    s += t[q];
  }
  red[tid] = s;
  __syncthreads();
  for (int st = 128; st > 0; st >>= 1) {
    if (tid < st) red[tid] += red[tid + st];
    __syncthreads();
  }
  const float mean = red[0] * (1.f / DM);
  __syncthreads();
  float vs = 0.f;
#pragma unroll
  for (int q = 0; q < 4; ++q) {
    float d0 = t[q] - mean;
    vs += d0 * d0;
  }
  red[tid] = vs;
  __syncthreads();
  for (int st = 128; st > 0; st >>= 1) {
    if (tid < st) red[tid] += red[tid + st];
    __syncthreads();
  }
  const float rstd = rsqrtf(red[0] * (1.f / DM) + 1e-5f);
#pragma unroll
  for (int q = 0; q < 4; ++q) {
    int c = tid + q * 256;
    const float val = (t[q] - mean) * rstd * g[c] + beta[c];
    xh[(size_t)r * DM + c] = (f16)val;
  }
}

// ln2: out = LN(x_h + y2a + y2b + b2), fp32 out.
__global__ __launch_bounds__(256) void ln2_kernel(
    const f16* __restrict__ xh, const f16* __restrict__ y2a,
    const f16* __restrict__ y2b, const float* __restrict__ b2,
    const float* __restrict__ g, const float* __restrict__ beta,
    float* __restrict__ out) {
  const int r = blockIdx.x, tid = threadIdx.x;
  __shared__ float red[256];
  float t[4];
  float s = 0.f;
#pragma unroll
  for (int q = 0; q < 4; ++q) {
    int c = tid + q * 256;
    t[q] = (float)xh[(size_t)r * DM + c] + (float)y2a[(size_t)r * DM + c] +
           (float)y2b[(size_t)r * DM + c] + b2[c];
    s += t[q];
  }
  red[tid] = s;
  __syncthreads();
  for (int st = 128; st > 0; st >>= 1) {
    if (tid < st) red[tid] += red[tid + st];
    __syncthreads();
  }
  const float mean = red[0] * (1.f / DM);
  __syncthreads();
  float vs = 0.f;
#pragma unroll
  for (int q = 0; q < 4; ++q) {
    float d0 = t[q] - mean;
    vs += d0 * d0;
  }
  red[tid] = vs;
  __syncthreads();
  for (int st = 128; st > 0; st >>= 1) {
    if (tid < st) red[tid] += red[tid + st];
    __syncthreads();
  }
  const float rstd = rsqrtf(red[0] * (1.f / DM) + 1e-5f);
#pragma unroll
  for (int q = 0; q < 4; ++q) {
    int c = tid + q * 256;
    out[(size_t)r * DM + c] = (t[q] - mean) * rstd * g[c] + beta[c];
  }
}

extern "C" void kernel_launch(void* const* d_in, const int* in_sizes, int n_in,
                              void* d_out, int out_size, void* d_ws, size_t ws_size,
                              hipStream_t stream) {
  const int o = (n_in >= 17) ? 1 : 0;
  const float* inputs = (const float*)d_in[0];
  const float* r      = (const float*)d_in[1];
  const float* u      = (const float*)d_in[2];
  const float* v      = (const float*)d_in[3];
  const float* memp   = (const float*)d_in[4];
  const float* W_qkv  = (const float*)d_in[5 + o];
  const float* W_r    = (const float*)d_in[6 + o];
  const float* W_o    = (const float*)d_in[7 + o];
  const float* ln1_g  = (const float*)d_in[8 + o];
  const float* ln1_b  = (const float*)d_in[9 + o];
  const float* ln2_g  = (const float*)d_in[10 + o];
  const float* ln2_b  = (const float*)d_in[11 + o];
  const float* W1     = (const float*)d_in[12 + o];
  const float* b1     = (const float*)d_in[13 + o];
  const float* W2     = (const float*)d_in[14 + o];
  const float* b2     = (const float*)d_in[15 + o];

  // Workspace liveness (peak 54,525,952 B; ws >= 58,720,256 per R0 layout):
  // phase 1: WqkvT@0 | r16@6291456 | WrT@9437184 | qkv@11534336 |
  //          rh@49283072 (ends 52428800) | WoT@52428800 (+2.1M, survives
  //          fattn: fattn writes only ctx_h@0..8.4M) | cat_h@d_out
  // phase 2: ctx_h@0 (fattn out) | ya@10485760 | yb@18874368 |
  //          x_h@27262976 | W1T@35651584 | W2T@44040192 | h_hi@0 (Wo dead)
  //          h_lo@d_out | y2a@18874368 (over yb) | y2b@35651584 (over W1T)
  char* ws = (char*)d_ws;
  f16*  WqkvT = (f16*)(ws);
  f16*  r16   = (f16*)(ws + 6291456);
  f16*  WrT   = (f16*)(ws + 9437184);
  bf16* qkv   = (bf16*)(ws + 11534336);
  bf16* rh    = (bf16*)(ws + 49283072);
  f16*  WoT   = (f16*)(ws + 52428800);
  f16*  cat_h = (f16*)d_out;
  f16*  ctx_h = (f16*)(ws);
  f16*  ya    = (f16*)(ws + 10485760);
  f16*  yb    = (f16*)(ws + 18874368);
  f16*  x_h   = (f16*)(ws + 27262976);
  f16*  W1T   = (f16*)(ws + 35651584);
  f16*  h_hi  = (f16*)(ws);
  f16*  h_lo  = (f16*)d_out;
  f16*  W2T   = (f16*)(ws + 44040192);
  f16*  y2a   = (f16*)(ws + 18874368);
  f16*  y2b   = (f16*)(ws + 35651584);

  dim3 blk(256);
  const int BIG = 1 << 30;

  // --- phase 1: converts + weight transposes + merged GEMM + attention ---
  convh3_kernel<<<dim3(7680), blk, 0, stream>>>(
      memp, inputs, r, cat_h, cat_h + (size_t)2048 * 1024, r16);
  // {W_qkv: 768 tiles, W_r: 256, W_o: 256} in one launch
  convTm_kernel<<<dim3(1280), blk, 0, stream>>>(
      W_qkv, WqkvT, 1024, 3072, 48,
      768, W_r, WrT, 1024, 1024, 16,
      1024, W_o, WoT, 1024, 1024, 16);
  // merged phase-1 GEMMs (uniform 64x128xK=1024 tiles):
  //  d0: mem rows x kv-cols [1024,3072): 16x32 = 512 blocks
  //  d1: input rows x all cols:          24x64 = 1536 blocks
  //  d2: r16 x WrT -> rh:                 8x24 = 192 blocks
  hgemm3_kernel<<<dim3(2240), blk, 0, stream>>>(
      cat_h, WqkvT + (size_t)1024 * 1024, qkv + 1024, 3072, 16,
      512, cat_h + (size_t)2048 * 1024, WqkvT, qkv + (size_t)2048 * 3072, 3072, 24,
      2048, r16, WrT, rh, 1024, 8);
  fattn_kernel<<<dim3(1024), blk, 0, stream>>>(qkv, rh, u, v, ctx_h);

  // --- phase 2: W1/W2 transposes + output proj + LN1 + MLP + LN2 ---
  convTm_kernel<<<dim3(2048), blk, 0, stream>>>(
      W1, W1T, 1024, 4096, 64,
      1024, W2, W2T, 4096, 1024, 16,
      2048, nullptr, nullptr, 0, 0, 1);
  hgemm_kernel<f16, 64><<<dim3(8, 128), blk, 0, stream>>>(
      ctx_h, WoT, ya, 1024, 1024, nullptr, 0,
      nullptr, nullptr, BIG, yb, nullptr, 2);
  ln1_kernel<<<dim3(4096), blk, 0, stream>>>(ya, yb, inputs, ln1_g, ln1_b, x_h);
  hgemm_kernel<f16, 128><<<dim3(32, 32), blk, 0, stream>>>(
      x_h, W1T, h_lo, 4096, 1024, b1, 1,
      x_h + (size_t)2048 * 1024, h_hi, 2048, nullptr, nullptr, 1);
  hgemm_kernel<f16, 64><<<dim3(8, 128), blk, 0, stream>>>(
      h_lo, W2T, y2a, 1024, 4096, nullptr, 0,
      h_hi, y2a + (size_t)2048 * 1024, 2048,
      y2b, y2b + (size_t)2048 * 1024, 2);
  ln2_kernel<<<dim3(4096), blk, 0, stream>>>(x_h, y2a, y2b, b2, ln2_g, ln2_b,
                                             (float*)d_out);
}